// Round 1
// baseline (577.690 us; speedup 1.0000x reference)
//
#include <hip/hip_runtime.h>

// Problem constants (from reference): B=64, TQ=1, TK=2048, QD=KD=512, U=1024, H=8, D=128
#define B_   64
#define TK_  2048
#define KD_  512
#define U_   1024
#define H_   8
#define D_   128
#define MT   64              // t-rows per workgroup tile
#define APAD 8               // pad 8 bf16 (16B) -> 2-way LDS bank conflicts only (free)
#define ASTR (KD_ + APAD)    // 520 shorts per row

typedef float f32x4 __attribute__((ext_vector_type(4)));
typedef short short8 __attribute__((ext_vector_type(8)));

__device__ __forceinline__ short f2bf(float f) {
    unsigned u = __float_as_uint(f);
    u += 0x7fffu + ((u >> 16) & 1u);          // round-to-nearest-even
    return (short)(u >> 16);
}
__device__ __forceinline__ float bf2f(short s) {
    return __uint_as_float(((unsigned)(unsigned short)s) << 16);
}
__device__ __forceinline__ float tanh_fast(float x) {
    // tanh(x) = 1 - 2/(1+exp(2x)); exact at +-inf saturation, ~1e-6 rel err
    float e = __builtin_amdgcn_exp2f(x * 2.885390081777927f);   // exp(2x)
    return 1.0f - 2.0f * __builtin_amdgcn_rcpf(1.0f + e);
}

// ---------------- setup kernel 1: normed_v = g * v * rsqrt(sum v^2) ----------------
__global__ void nv_kernel(const float* __restrict__ v, float* __restrict__ wsNV) {
    __shared__ float red[D_];
    int tid = threadIdx.x;
    float x = v[tid];
    red[tid] = x * x;
    __syncthreads();
    if (tid == 0) {
        float s = 0.f;
        for (int i = 0; i < D_; ++i) s += red[i];
        red[0] = rsqrtf(s) * 0.08838834764831845f;   // 1/sqrt(128)
    }
    __syncthreads();
    wsNV[tid] = x * red[0];
}

// ---------------- setup kernel 2: qb[b][u] = query[b,:].Wq[u,:] + bq[u] + bk[u] ----------------
// bk folded in since score arg is (key.Wk + bk) + (query.Wq + bq)
__global__ void q_kernel(const float* __restrict__ query, const float* __restrict__ Wq,
                         const float* __restrict__ bq, const float* __restrict__ bk,
                         float* __restrict__ wsQ) {
    __shared__ float qrow[KD_];
    int b = blockIdx.x, ug = blockIdx.y, tid = threadIdx.x;
    if (tid < 128) ((float4*)qrow)[tid] = ((const float4*)(query + (size_t)b * KD_))[tid];
    __syncthreads();
    int u = ug * 256 + tid;
    const float4* wq = (const float4*)(Wq + (size_t)u * KD_);
    const float4* q4 = (const float4*)qrow;
    float acc = 0.f;
#pragma unroll 8
    for (int i = 0; i < KD_ / 4; ++i) {
        float4 a = q4[i], w = wq[i];
        acc += a.x * w.x + a.y * w.y + a.z * w.z + a.w * w.w;
    }
    wsQ[(size_t)b * U_ + u] = acc + bq[u] + bk[u];
}

// ---------------- setup kernel 3: swizzle Wk (fp32) into fragment-major bf16 ----------------
// frag slot = u_blk*16 + kstep; within slot: lane l holds 8 bf16:
//   u = u_blk*16 + (l&15), k = kstep*32 + (l>>4)*8 + j   (MFMA B-operand layout)
// -> main kernel B loads are perfectly coalesced global_load_dwordx4
__global__ void swz_kernel(const float* __restrict__ Wk, short* __restrict__ wsB) {
    int g = blockIdx.x * 256 + threadIdx.x;   // 0..65535 lane-frags
    int slot = g >> 6, l = g & 63;
    int ublk = slot >> 4, ks = slot & 15;
    int u = ublk * 16 + (l & 15);
    int k0 = ks * 32 + ((l >> 4) << 3);
    const float* src = Wk + (size_t)u * KD_ + k0;
    short8 o;
#pragma unroll
    for (int j = 0; j < 8; ++j) o[j] = f2bf(src[j]);
    *(short8*)(wsB + (size_t)g * 8) = o;
}

// ---------------- main fused kernel ----------------
// grid: 2048 = 64 b * 32 t-tiles; block 256 (4 waves); 2 WGs/CU (LDS 70.7 KB)
__global__ __launch_bounds__(256, 2) void attn_kernel(
    const float* __restrict__ key, const short* __restrict__ wsB,
    const float* __restrict__ wsQ, const float* __restrict__ wsNV,
    float* __restrict__ out)
{
    __shared__ short As[MT * ASTR];   // bf16 key tile, reused for GEMM-A and value
    __shared__ float S[MT][H_];       // scores
    __shared__ float Wt[MT][H_];      // softmax weights

    int bx = blockIdx.x;
    int b = bx & 63, tt = bx >> 6;
    int tid = threadIdx.x;

    // ---- stage key tile [64 x 512] fp32 -> bf16 LDS (coalesced float4) ----
    const float4* src = (const float4*)(key + ((size_t)b * TK_ + (size_t)tt * MT) * KD_);
#pragma unroll 8
    for (int j = 0; j < 32; ++j) {
        int i = tid + j * 256;                 // 8192 float4 total
        float4 v = src[i];
        int t = i >> 7, c4 = (i & 127) << 2;
        short4 h4;
        h4.x = f2bf(v.x); h4.y = f2bf(v.y); h4.z = f2bf(v.z); h4.w = f2bf(v.w);
        *(short4*)&As[t * ASTR + c4] = h4;
    }
    __syncthreads();

    int w = tid >> 6, l = tid & 63;
    int l15 = l & 15, lq = l >> 4;
    const short8* bp = (const short8*)wsB;

    // each (wave, chunk) covers exactly one head: u_base = c*512 + w*128
    for (int c = 0; c < 2; ++c) {
        int ub = c * 512 + w * 128;
        int ub16 = ub >> 4;
        int bidx = ub16 * 1024 + l;            // short8 index for nf=0, ks=0

        f32x4 acc[4][8] = {};                  // 4 m-frags x 8 n-frags

        short8 bc[8];
#pragma unroll
        for (int nf = 0; nf < 8; ++nf) bc[nf] = bp[bidx + nf * 1024];

#pragma unroll 1
        for (int ks = 0; ks < 16; ++ks) {
            short8 bn[8];
            if (ks < 15) {
#pragma unroll
                for (int nf = 0; nf < 8; ++nf) bn[nf] = bp[bidx + nf * 1024 + (ks + 1) * 64];
            }
            short8 a[4];
#pragma unroll
            for (int mf = 0; mf < 4; ++mf)
                a[mf] = *(const short8*)&As[(mf * 16 + l15) * ASTR + ks * 32 + (lq << 3)];
#pragma unroll
            for (int mf = 0; mf < 4; ++mf)
#pragma unroll
                for (int nf = 0; nf < 8; ++nf)
                    acc[mf][nf] = __builtin_amdgcn_mfma_f32_16x16x32_bf16(a[mf], bc[nf], acc[mf][nf], 0, 0, 0);
            if (ks < 15) {
#pragma unroll
                for (int nf = 0; nf < 8; ++nf) bc[nf] = bn[nf];
            }
        }

        // ---- score epilogue: s[t][h] = sum_d nv[d] * tanh(k + qb) ----
        float qv[8], nv[8];
#pragma unroll
        for (int nf = 0; nf < 8; ++nf) {
            int d = nf * 16 + l15;
            qv[nf] = wsQ[(size_t)b * U_ + ub + d];
            nv[nf] = wsNV[d];
        }
        int h = ub >> 7;                       // = c*4 + w
#pragma unroll
        for (int mf = 0; mf < 4; ++mf)
#pragma unroll
            for (int r = 0; r < 4; ++r) {
                float p = 0.f;
#pragma unroll
                for (int nf = 0; nf < 8; ++nf)
                    p += nv[nf] * tanh_fast(acc[mf][nf][r] + qv[nf]);
                // C/D layout: row t = mf*16 + lq*4 + r, col = nf*16 + l15
                // reduce the 16 columns held across l&15 lanes (lq preserved)
                p += __shfl_xor(p, 1);
                p += __shfl_xor(p, 2);
                p += __shfl_xor(p, 4);
                p += __shfl_xor(p, 8);
                if (l15 == 0) S[mf * 16 + lq * 4 + r][h] = p;
            }
    }
    __syncthreads();

    // ---- softmax over HEADS per t (legacy F.softmax dim=1) ----
    if (tid < MT) {
        float sv[H_];
        float mx = -1e30f;
#pragma unroll
        for (int h = 0; h < H_; ++h) { sv[h] = S[tid][h]; mx = fmaxf(mx, sv[h]); }
        float sum = 0.f;
#pragma unroll
        for (int h = 0; h < H_; ++h) {
            sv[h] = __builtin_amdgcn_exp2f((sv[h] - mx) * 1.4426950408889634f);
            sum += sv[h];
        }
        float inv = __builtin_amdgcn_rcpf(sum);
#pragma unroll
        for (int h = 0; h < H_; ++h) Wt[tid][h] = sv[h] * inv;
    }
    __syncthreads();

    // ---- partial context: ctx[h][d] = sum_t w[t][h] * key[t][d]; atomics into out ----
    int dg = (tid & 127) << 2;        // d group of 4
    int hb = (tid >> 7) << 2;         // h base: 0 or 4
    float cacc[4][4] = {};
    for (int t = 0; t < MT; ++t) {
        short4 kk = *(const short4*)&As[t * ASTR + dg];
        float k0 = bf2f(kk.x), k1 = bf2f(kk.y), k2 = bf2f(kk.z), k3 = bf2f(kk.w);
#pragma unroll
        for (int j = 0; j < 4; ++j) {
            float wt = Wt[t][hb + j];
            cacc[j][0] += wt * k0; cacc[j][1] += wt * k1;
            cacc[j][2] += wt * k2; cacc[j][3] += wt * k3;
        }
    }
    float* ob = out + (size_t)b * (H_ * KD_);
#pragma unroll
    for (int j = 0; j < 4; ++j)
#pragma unroll
        for (int d = 0; d < 4; ++d)
            atomicAdd(&ob[(hb + j) * KD_ + dg + d], cacc[j][d]);
}

extern "C" void kernel_launch(void* const* d_in, const int* in_sizes, int n_in,
                              void* d_out, int out_size, void* d_ws, size_t ws_size,
                              hipStream_t stream) {
    const float* query = (const float*)d_in[0];
    const float* key   = (const float*)d_in[1];
    const float* Wq    = (const float*)d_in[2];
    const float* bq    = (const float*)d_in[3];
    const float* Wk    = (const float*)d_in[4];
    const float* bk    = (const float*)d_in[5];
    const float* v     = (const float*)d_in[6];
    float* out = (float*)d_out;

    char* ws = (char*)d_ws;
    float* wsNV = (float*)ws;                  // 512 B
    float* wsQ  = (float*)(ws + 4096);         // 256 KB (qb = q + bq + bk)
    short* wsB  = (short*)(ws + 524288);       // 1 MB swizzled bf16 Wk

    hipMemsetAsync(d_out, 0, (size_t)out_size * sizeof(float), stream);
    nv_kernel<<<1, 128, 0, stream>>>(v, wsNV);
    q_kernel<<<dim3(64, 4), 256, 0, stream>>>(query, Wq, bq, bk, wsQ);
    swz_kernel<<<256, 256, 0, stream>>>(Wk, wsB);
    attn_kernel<<<2048, 256, 0, stream>>>(key, wsB, wsQ, wsNV, out);
}

// Round 2
// 528.901 us; speedup vs baseline: 1.0922x; 1.0922x over previous
//
#include <hip/hip_runtime.h>

// Problem constants (from reference): B=64, TQ=1, TK=2048, QD=KD=512, U=1024, H=8, D=128
#define B_   64
#define TK_  2048
#define KD_  512
#define U_   1024
#define H_   8
#define D_   128
#define MT   64              // t-rows per workgroup tile
#define APAD 8               // pad 8 bf16 (16B) -> 2-way LDS bank conflicts only (free)
#define ASTR (KD_ + APAD)    // 520 shorts per row
#define NTILE (TK_ / MT)     // 32 t-tiles per batch
#define GRID (B_ * NTILE)    // 2048 workgroups

typedef float f32x4 __attribute__((ext_vector_type(4)));
typedef short short8 __attribute__((ext_vector_type(8)));

__device__ __forceinline__ short f2bf(float f) {
    unsigned u = __float_as_uint(f);
    u += 0x7fffu + ((u >> 16) & 1u);          // round-to-nearest-even
    return (short)(u >> 16);
}
__device__ __forceinline__ float bf2f(short s) {
    return __uint_as_float(((unsigned)(unsigned short)s) << 16);
}
__device__ __forceinline__ float tanh_fast(float x) {
    // tanh(x) = 1 - 2/(1+exp(2x)); exact at +-inf saturation, ~1e-6 rel err
    float e = __builtin_amdgcn_exp2f(x * 2.885390081777927f);   // exp(2x)
    return 1.0f - 2.0f * __builtin_amdgcn_rcpf(1.0f + e);
}

// ---------------- setup kernel 1: normed_v = g * v * rsqrt(sum v^2) ----------------
__global__ void nv_kernel(const float* __restrict__ v, float* __restrict__ wsNV) {
    __shared__ float red[D_];
    int tid = threadIdx.x;
    float x = v[tid];
    red[tid] = x * x;
    __syncthreads();
    if (tid == 0) {
        float s = 0.f;
        for (int i = 0; i < D_; ++i) s += red[i];
        red[0] = rsqrtf(s) * 0.08838834764831845f;   // 1/sqrt(128)
    }
    __syncthreads();
    wsNV[tid] = x * red[0];
}

// ---------------- setup kernel 2: qb[b][u] = query[b,:].Wq[u,:] + bq[u] + bk[u] ----------------
__global__ void q_kernel(const float* __restrict__ query, const float* __restrict__ Wq,
                         const float* __restrict__ bq, const float* __restrict__ bk,
                         float* __restrict__ wsQ) {
    __shared__ float qrow[KD_];
    int b = blockIdx.x, ug = blockIdx.y, tid = threadIdx.x;
    if (tid < 128) ((float4*)qrow)[tid] = ((const float4*)(query + (size_t)b * KD_))[tid];
    __syncthreads();
    int u = ug * 256 + tid;
    const float4* wq = (const float4*)(Wq + (size_t)u * KD_);
    const float4* q4 = (const float4*)qrow;
    float acc = 0.f;
#pragma unroll 8
    for (int i = 0; i < KD_ / 4; ++i) {
        float4 a = q4[i], w = wq[i];
        acc += a.x * w.x + a.y * w.y + a.z * w.z + a.w * w.w;
    }
    wsQ[(size_t)b * U_ + u] = acc + bq[u] + bk[u];
}

// ---------------- setup kernel 3: swizzle Wk (fp32) into fragment-major bf16 ----------------
// frag slot = u_blk*16 + kstep; within slot: lane l holds 8 bf16:
//   u = u_blk*16 + (l&15), k = kstep*32 + (l>>4)*8 + j   (MFMA B-operand layout)
__global__ void swz_kernel(const float* __restrict__ Wk, short* __restrict__ wsB) {
    int g = blockIdx.x * 256 + threadIdx.x;   // 0..65535 lane-frags
    int slot = g >> 6, l = g & 63;
    int ublk = slot >> 4, ks = slot & 15;
    int u = ublk * 16 + (l & 15);
    int k0 = ks * 32 + ((l >> 4) << 3);
    const float* src = Wk + (size_t)u * KD_ + k0;
    short8 o;
#pragma unroll
    for (int j = 0; j < 8; ++j) o[j] = f2bf(src[j]);
    *(short8*)(wsB + (size_t)g * 8) = o;
}

// ---------------- main fused kernel ----------------
// grid: 2048 = 64 b * 32 t-tiles; block 256 (4 waves); 2 WGs/CU (LDS ~70.7 KB)
// ATOMIC=false: write per-block partial ctx to `outp` (ws), reduced by reduce_kernel.
// ATOMIC=true : legacy fallback, atomicAdd into out (requires pre-zeroed out).
template <bool ATOMIC>
__global__ __launch_bounds__(256, 2) void attn_kernel(
    const float* __restrict__ key, const short* __restrict__ wsB,
    const float* __restrict__ wsQ, const float* __restrict__ wsNV,
    float* __restrict__ outp)
{
    __shared__ short As[MT * ASTR];   // bf16 key tile, reused for GEMM-A and value
    __shared__ float S[MT][H_];       // scores
    __shared__ float Wt[MT][H_];      // softmax weights

    int bx = blockIdx.x;
    int b = bx & 63, tt = bx >> 6;
    int tid = threadIdx.x;

    // ---- stage key tile [64 x 512] fp32 -> bf16 LDS (coalesced float4) ----
    const float4* src = (const float4*)(key + ((size_t)b * TK_ + (size_t)tt * MT) * KD_);
#pragma unroll 8
    for (int j = 0; j < 32; ++j) {
        int i = tid + j * 256;                 // 8192 float4 total
        float4 v = src[i];
        int t = i >> 7, c4 = (i & 127) << 2;
        short4 h4;
        h4.x = f2bf(v.x); h4.y = f2bf(v.y); h4.z = f2bf(v.z); h4.w = f2bf(v.w);
        *(short4*)&As[t * ASTR + c4] = h4;
    }
    __syncthreads();

    int w = tid >> 6, l = tid & 63;
    int l15 = l & 15, lq = l >> 4;
    const short8* bp = (const short8*)wsB;

    // each (wave, chunk) covers exactly one head: u_base = c*512 + w*128
    for (int c = 0; c < 2; ++c) {
        int ub = c * 512 + w * 128;
        int ub16 = ub >> 4;
        int bidx = ub16 * 1024 + l;            // short8 index for nf=0, ks=0

        f32x4 acc[4][8] = {};                  // 4 m-frags x 8 n-frags

        short8 bc[8];
#pragma unroll
        for (int nf = 0; nf < 8; ++nf) bc[nf] = bp[bidx + nf * 1024];

#pragma unroll 1
        for (int ks = 0; ks < 16; ++ks) {
            short8 bn[8];
            if (ks < 15) {
#pragma unroll
                for (int nf = 0; nf < 8; ++nf) bn[nf] = bp[bidx + nf * 1024 + (ks + 1) * 64];
            }
            short8 a[4];
#pragma unroll
            for (int mf = 0; mf < 4; ++mf)
                a[mf] = *(const short8*)&As[(mf * 16 + l15) * ASTR + ks * 32 + (lq << 3)];
#pragma unroll
            for (int mf = 0; mf < 4; ++mf)
#pragma unroll
                for (int nf = 0; nf < 8; ++nf)
                    acc[mf][nf] = __builtin_amdgcn_mfma_f32_16x16x32_bf16(a[mf], bc[nf], acc[mf][nf], 0, 0, 0);
            if (ks < 15) {
#pragma unroll
                for (int nf = 0; nf < 8; ++nf) bc[nf] = bn[nf];
            }
        }

        // ---- score epilogue: s[t][h] = sum_d nv[d] * tanh(k + qb) ----
        float qv[8], nv[8];
#pragma unroll
        for (int nf = 0; nf < 8; ++nf) {
            int d = nf * 16 + l15;
            qv[nf] = wsQ[(size_t)b * U_ + ub + d];
            nv[nf] = wsNV[d];
        }
        int h = ub >> 7;                       // = c*4 + w
#pragma unroll
        for (int mf = 0; mf < 4; ++mf)
#pragma unroll
            for (int r = 0; r < 4; ++r) {
                float p = 0.f;
#pragma unroll
                for (int nf = 0; nf < 8; ++nf)
                    p += nv[nf] * tanh_fast(acc[mf][nf][r] + qv[nf]);
                // C/D layout: row t = mf*16 + lq*4 + r, col = nf*16 + l15
                p += __shfl_xor(p, 1);
                p += __shfl_xor(p, 2);
                p += __shfl_xor(p, 4);
                p += __shfl_xor(p, 8);
                if (l15 == 0) S[mf * 16 + lq * 4 + r][h] = p;
            }
    }
    __syncthreads();

    // ---- softmax over HEADS per t (legacy F.softmax dim=1) ----
    if (tid < MT) {
        float sv[H_];
        float mx = -1e30f;
#pragma unroll
        for (int h = 0; h < H_; ++h) { sv[h] = S[tid][h]; mx = fmaxf(mx, sv[h]); }
        float sum = 0.f;
#pragma unroll
        for (int h = 0; h < H_; ++h) {
            sv[h] = __builtin_amdgcn_exp2f((sv[h] - mx) * 1.4426950408889634f);
            sum += sv[h];
        }
        float inv = __builtin_amdgcn_rcpf(sum);
#pragma unroll
        for (int h = 0; h < H_; ++h) Wt[tid][h] = sv[h] * inv;
    }
    __syncthreads();

    // ---- partial context: ctx[h][d] = sum_t w[t][h] * key[t][d] ----
    int dg = (tid & 127) << 2;        // d group of 4
    int hb = (tid >> 7) << 2;         // h base: 0 or 4
    float cacc[4][4] = {};
    for (int t = 0; t < MT; ++t) {
        short4 kk = *(const short4*)&As[t * ASTR + dg];
        float k0 = bf2f(kk.x), k1 = bf2f(kk.y), k2 = bf2f(kk.z), k3 = bf2f(kk.w);
#pragma unroll
        for (int j = 0; j < 4; ++j) {
            float wt = Wt[t][hb + j];
            cacc[j][0] += wt * k0; cacc[j][1] += wt * k1;
            cacc[j][2] += wt * k2; cacc[j][3] += wt * k3;
        }
    }
    if (ATOMIC) {
        float* ob = outp + (size_t)b * (H_ * KD_);
#pragma unroll
        for (int j = 0; j < 4; ++j)
#pragma unroll
            for (int d = 0; d < 4; ++d)
                atomicAdd(&ob[(hb + j) * KD_ + dg + d], cacc[j][d]);
    } else {
        // fully coalesced float4 stores: block-private partial [8][512]
        float* pb = outp + (size_t)bx * (H_ * KD_);
#pragma unroll
        for (int j = 0; j < 4; ++j)
            *(f32x4*)&pb[(hb + j) * KD_ + dg] = *(f32x4*)&cacc[j][0];
    }
}

// ---------------- reduce kernel: out[b][u] = sum_tt partial[tt*64+b][u] ----------------
__global__ void reduce_kernel(const float* __restrict__ partial, float* __restrict__ out) {
    int o = blockIdx.x * 256 + threadIdx.x;   // float4 index, 65536 total
    int b = o >> 10;                          // 1024 float4 per batch
    int u4 = o & 1023;
    const f32x4* p4 = (const f32x4*)partial;
    f32x4 s = {0.f, 0.f, 0.f, 0.f};
#pragma unroll 8
    for (int tt = 0; tt < NTILE; ++tt)
        s += p4[((size_t)(tt * 64 + b)) * 1024 + u4];
    ((f32x4*)out)[o] = s;
}

extern "C" void kernel_launch(void* const* d_in, const int* in_sizes, int n_in,
                              void* d_out, int out_size, void* d_ws, size_t ws_size,
                              hipStream_t stream) {
    const float* query = (const float*)d_in[0];
    const float* key   = (const float*)d_in[1];
    const float* Wq    = (const float*)d_in[2];
    const float* bq    = (const float*)d_in[3];
    const float* Wk    = (const float*)d_in[4];
    const float* bk    = (const float*)d_in[5];
    const float* v     = (const float*)d_in[6];
    float* out = (float*)d_out;

    char* ws = (char*)d_ws;
    float* wsNV = (float*)ws;                       // 512 B
    float* wsQ  = (float*)(ws + 4096);              // 256 KB (qb = q + bq + bk)
    short* wsB  = (short*)(ws + 524288);            // 1 MB swizzled bf16 Wk
    float* wsP  = (float*)(ws + 2 * 1024 * 1024);   // 33.55 MB partial contexts

    size_t need = 2 * 1024 * 1024 + (size_t)GRID * (H_ * KD_) * sizeof(float);

    nv_kernel<<<1, 128, 0, stream>>>(v, wsNV);
    q_kernel<<<dim3(64, 4), 256, 0, stream>>>(query, Wq, bq, bk, wsQ);
    swz_kernel<<<256, 256, 0, stream>>>(Wk, wsB);

    if (ws_size >= need) {
        attn_kernel<false><<<GRID, 256, 0, stream>>>(key, wsB, wsQ, wsNV, wsP);
        reduce_kernel<<<256, 256, 0, stream>>>(wsP, out);
    } else {
        hipMemsetAsync(d_out, 0, (size_t)out_size * sizeof(float), stream);
        attn_kernel<true><<<GRID, 256, 0, stream>>>(key, wsB, wsQ, wsNV, out);
    }
}